// Round 1
// baseline (3059.068 us; speedup 1.0000x reference)
//
#include <hip/hip_runtime.h>
#include <math.h>

#define N_NODES 50000
#define N_EDGES 800000
#define HD 128          // H*D = 4*32
#define GG 1024
#define NEG_SLOPE 0.2f

__device__ __forceinline__ void atomicMaxF(float* addr, float val) {
    // two-sided int-punning float max; smax initialized to -inf
    if (val >= 0.f) atomicMax((int*)addr, __float_as_int(val));
    else            atomicMin((unsigned int*)addr, (unsigned int)__float_as_int(val));
}

// C[n,128] = A[n,K] @ W[K,128] + bias   (fp32, vector ALU)
// tile: 64 rows x 128 cols, K chunked by 64. thread = 2 consecutive rows x 16 cols.
template<int K>
__launch_bounds__(256)
__global__ void gemm_bias(const float* __restrict__ A, const float* __restrict__ W,
                          const float* __restrict__ bias, float* __restrict__ C, int n)
{
    constexpr int KC = 64;
    constexpr int NCHUNK = K / KC;
    __shared__ float Ws[KC * 128];        // 32 KB
    __shared__ float Xs[64 * (KC + 1)];   // 16.6 KB, +1 pad vs bank conflicts
    const int tid  = threadIdx.x;
    const int row0 = blockIdx.x * 64;
    const int cg   = (tid & 7) * 16;      // col base
    const int r0   = (tid >> 3) * 2;      // row pair base (0..62)

    float acc[2][16];
    #pragma unroll
    for (int i = 0; i < 2; i++)
        #pragma unroll
        for (int j = 0; j < 16; j++) acc[i][j] = 0.f;

    for (int kc = 0; kc < NCHUNK; kc++) {
        // stage W chunk: contiguous KC*128 floats
        const float4* wsrc = (const float4*)(W + (size_t)kc * KC * 128);
        float4* wdst = (float4*)Ws;
        #pragma unroll
        for (int i = 0; i < (KC * 32) / 256; i++)
            wdst[tid + i * 256] = wsrc[tid + i * 256];
        // stage X tile chunk (coalesced rows)
        for (int i = tid; i < 64 * KC; i += 256) {
            int r = i >> 6;          // i / KC (KC==64)
            int k = i & 63;
            int row = row0 + r;
            Xs[r * (KC + 1) + k] = (row < n) ? A[(size_t)row * K + kc * KC + k] : 0.f;
        }
        __syncthreads();
        #pragma unroll 4
        for (int k = 0; k < KC; k++) {
            const float4 w0 = *(const float4*)&Ws[k * 128 + cg + 0];
            const float4 w1 = *(const float4*)&Ws[k * 128 + cg + 4];
            const float4 w2 = *(const float4*)&Ws[k * 128 + cg + 8];
            const float4 w3 = *(const float4*)&Ws[k * 128 + cg + 12];
            const float x0 = Xs[(r0 + 0) * (KC + 1) + k];
            const float x1 = Xs[(r0 + 1) * (KC + 1) + k];
            acc[0][0] += x0 * w0.x; acc[0][1] += x0 * w0.y; acc[0][2] += x0 * w0.z; acc[0][3] += x0 * w0.w;
            acc[0][4] += x0 * w1.x; acc[0][5] += x0 * w1.y; acc[0][6] += x0 * w1.z; acc[0][7] += x0 * w1.w;
            acc[0][8] += x0 * w2.x; acc[0][9] += x0 * w2.y; acc[0][10]+= x0 * w2.z; acc[0][11]+= x0 * w2.w;
            acc[0][12]+= x0 * w3.x; acc[0][13]+= x0 * w3.y; acc[0][14]+= x0 * w3.z; acc[0][15]+= x0 * w3.w;
            acc[1][0] += x1 * w0.x; acc[1][1] += x1 * w0.y; acc[1][2] += x1 * w0.z; acc[1][3] += x1 * w0.w;
            acc[1][4] += x1 * w1.x; acc[1][5] += x1 * w1.y; acc[1][6] += x1 * w1.z; acc[1][7] += x1 * w1.w;
            acc[1][8] += x1 * w2.x; acc[1][9] += x1 * w2.y; acc[1][10]+= x1 * w2.z; acc[1][11]+= x1 * w2.w;
            acc[1][12]+= x1 * w3.x; acc[1][13]+= x1 * w3.y; acc[1][14]+= x1 * w3.z; acc[1][15]+= x1 * w3.w;
        }
        __syncthreads();
    }

    const float4 b0 = *(const float4*)&bias[cg + 0];
    const float4 b1 = *(const float4*)&bias[cg + 4];
    const float4 b2 = *(const float4*)&bias[cg + 8];
    const float4 b3 = *(const float4*)&bias[cg + 12];
    #pragma unroll
    for (int i = 0; i < 2; i++) {
        int row = row0 + r0 + i;
        if (row < n) {
            float4* cp = (float4*)(C + (size_t)row * 128 + cg);
            cp[0] = make_float4(acc[i][0] + b0.x, acc[i][1] + b0.y, acc[i][2] + b0.z, acc[i][3] + b0.w);
            cp[1] = make_float4(acc[i][4] + b1.x, acc[i][5] + b1.y, acc[i][6] + b1.z, acc[i][7] + b1.w);
            cp[2] = make_float4(acc[i][8] + b2.x, acc[i][9] + b2.y, acc[i][10]+ b2.z, acc[i][11]+ b2.w);
            cp[3] = make_float4(acc[i][12]+ b3.x, acc[i][13]+ b3.y, acc[i][14]+ b3.z, acc[i][15]+ b3.w);
        }
    }
}

__global__ void fill_neg_inf(float* __restrict__ p, int n) {
    int i = blockIdx.x * 256 + threadIdx.x;
    if (i < n) p[i] = -__builtin_inff();
}

// one wave per edge: score[e][h] = att_h . leaky_relu(xl[src] + xr[dst]); atomic segment-max
__launch_bounds__(256)
__global__ void edge_score(const float* __restrict__ xl, const float* __restrict__ xr,
                           const int* __restrict__ src, const int* __restrict__ dst,
                           const float* __restrict__ att,
                           float* __restrict__ score, float* __restrict__ smax)
{
    const int wave = (blockIdx.x * 256 + threadIdx.x) >> 6;
    const int lane = threadIdx.x & 63;
    if (wave >= N_EDGES) return;
    const int s = src[wave];
    const int d = dst[wave];
    const float2 a = *(const float2*)(xl + (size_t)s * HD + lane * 2);
    const float2 b = *(const float2*)(xr + (size_t)d * HD + lane * 2);
    const float2 w = *(const float2*)(att + lane * 2);
    float m0 = a.x + b.x; m0 = (m0 >= 0.f) ? m0 : NEG_SLOPE * m0;
    float m1 = a.y + b.y; m1 = (m1 >= 0.f) ? m1 : NEG_SLOPE * m1;
    float p = m0 * w.x + m1 * w.y;
    p += __shfl_xor(p, 1);
    p += __shfl_xor(p, 2);
    p += __shfl_xor(p, 4);
    p += __shfl_xor(p, 8);          // reduced over 16-lane head groups
    if ((lane & 15) == 0) {
        const int h = lane >> 4;
        score[(size_t)wave * 4 + h] = p;
        atomicMaxF(&smax[(size_t)d * 4 + h], p);
    }
}

// thread per (edge, head): expv + segment-sum denominator
__global__ void edge_exp(const int* __restrict__ dst, const float* __restrict__ smax,
                         float* __restrict__ score, float* __restrict__ denom)
{
    const int i = blockIdx.x * 256 + threadIdx.x;
    if (i >= N_EDGES * 4) return;
    const int e = i >> 2, h = i & 3;
    const int d = dst[e];
    const float v = expf(score[i] - smax[d * 4 + h]);
    score[i] = v;   // score buffer becomes expv
    unsafeAtomicAdd(&denom[d * 4 + h], v);
}

// one wave per edge: agg[dst] += alpha * xl[src]
__launch_bounds__(256)
__global__ void edge_agg(const float* __restrict__ xl, const float* __restrict__ expv,
                         const float* __restrict__ denom,
                         const int* __restrict__ src, const int* __restrict__ dst,
                         float* __restrict__ agg)
{
    const int wave = (blockIdx.x * 256 + threadIdx.x) >> 6;
    const int lane = threadIdx.x & 63;
    if (wave >= N_EDGES) return;
    const int s = src[wave];
    const int d = dst[wave];
    const int h = lane >> 4;
    const float alpha = expv[(size_t)wave * 4 + h] / denom[(size_t)d * 4 + h];
    const float2 v = *(const float2*)(xl + (size_t)s * HD + lane * 2);
    float* dp = agg + (size_t)d * HD + lane * 2;
    unsafeAtomicAdd(dp + 0, alpha * v.x);
    unsafeAtomicAdd(dp + 1, alpha * v.y);
}

__global__ void node_elu(const float* __restrict__ agg, const float* __restrict__ b,
                         float* __restrict__ hout)
{
    const int i = blockIdx.x * 256 + threadIdx.x;
    if (i >= N_NODES * HD) return;
    const float v = agg[i] + b[i & 127];
    hout[i] = (v > 0.f) ? v : expm1f(v);
}

__global__ void pool_accum(const float* __restrict__ h, const int* __restrict__ batch,
                           float* __restrict__ pooled)
{
    const int i = blockIdx.x * 256 + threadIdx.x;
    if (i >= N_NODES * HD) return;
    const int n = i >> 7;
    unsafeAtomicAdd(&pooled[(size_t)batch[n] * HD + (i & 127)], h[i]);
}

__global__ void cnt_accum(const int* __restrict__ batch, float* __restrict__ cnt)
{
    const int i = blockIdx.x * 256 + threadIdx.x;
    if (i < N_NODES) unsafeAtomicAdd(&cnt[batch[i]], 1.f);
}

// one wave per graph: out[g] = (pooled[g]/max(cnt,1)) . Wh + bh
__global__ void head(const float* __restrict__ pooled, const float* __restrict__ cnt,
                     const float* __restrict__ Wh, const float* __restrict__ bh,
                     float* __restrict__ out)
{
    const int g = (blockIdx.x * 256 + threadIdx.x) >> 6;
    const int lane = threadIdx.x & 63;
    if (g >= GG) return;
    const float2 p = *(const float2*)(pooled + (size_t)g * HD + lane * 2);
    const float2 w = *(const float2*)(Wh + lane * 2);
    float s = p.x * w.x + p.y * w.y;
    s += __shfl_xor(s, 1);
    s += __shfl_xor(s, 2);
    s += __shfl_xor(s, 4);
    s += __shfl_xor(s, 8);
    s += __shfl_xor(s, 16);
    s += __shfl_xor(s, 32);
    if (lane == 0) out[g] = s / fmaxf(cnt[g], 1.f) + bh[0];
}

extern "C" void kernel_launch(void* const* d_in, const int* in_sizes, int n_in,
                              void* d_out, int out_size, void* d_ws, size_t ws_size,
                              hipStream_t stream)
{
    const float* x     = (const float*)d_in[0];
    const int*   edge  = (const int*)d_in[1];
    const int*   batch = (const int*)d_in[2];
    const int*   src   = edge;              // edge_index[0]
    const int*   dst   = edge + N_EDGES;    // edge_index[1]
    const float* Wh    = (const float*)d_in[21];
    const float* bh    = (const float*)d_in[22];
    float* out = (float*)d_out;

    const size_t N128 = (size_t)N_NODES * HD;
    float* ws      = (float*)d_ws;
    float* buf_h   = ws;                         // N*128
    float* buf_xl  = buf_h  + N128;              // N*128
    float* buf_xr  = buf_xl + N128;              // N*128
    float* buf_agg = buf_xr + N128;              // N*128
    float* score   = buf_agg + N128;             // E*4 (scores, then expv)
    float* smax    = score + (size_t)N_EDGES * 4;// N*4
    float* denom   = smax  + (size_t)N_NODES * 4;// N*4
    float* pooled  = denom + (size_t)N_NODES * 4;// G*128
    float* cnt     = pooled + (size_t)GG * HD;   // G

    const float* hin = x;
    const int gemm_grid = (N_NODES + 63) / 64;

    for (int l = 0; l < 3; l++) {
        const float* Wl  = (const float*)d_in[3 + 6 * l];
        const float* bl  = (const float*)d_in[4 + 6 * l];
        const float* Wr  = (const float*)d_in[5 + 6 * l];
        const float* br  = (const float*)d_in[6 + 6 * l];
        const float* att = (const float*)d_in[7 + 6 * l];
        const float* bb  = (const float*)d_in[8 + 6 * l];

        hipMemsetAsync(buf_agg, 0, N128 * sizeof(float), stream);
        hipMemsetAsync(denom, 0, (size_t)N_NODES * 4 * sizeof(float), stream);
        fill_neg_inf<<<(N_NODES * 4 + 255) / 256, 256, 0, stream>>>(smax, N_NODES * 4);

        if (l == 0) {
            gemm_bias<64><<<gemm_grid, 256, 0, stream>>>(hin, Wl, bl, buf_xl, N_NODES);
            gemm_bias<64><<<gemm_grid, 256, 0, stream>>>(hin, Wr, br, buf_xr, N_NODES);
        } else {
            gemm_bias<128><<<gemm_grid, 256, 0, stream>>>(hin, Wl, bl, buf_xl, N_NODES);
            gemm_bias<128><<<gemm_grid, 256, 0, stream>>>(hin, Wr, br, buf_xr, N_NODES);
        }
        edge_score<<<N_EDGES / 4, 256, 0, stream>>>(buf_xl, buf_xr, src, dst, att, score, smax);
        edge_exp<<<(N_EDGES * 4 + 255) / 256, 256, 0, stream>>>(dst, smax, score, denom);
        edge_agg<<<N_EDGES / 4, 256, 0, stream>>>(buf_xl, score, denom, src, dst, buf_agg);
        node_elu<<<((int)N128 + 255) / 256, 256, 0, stream>>>(buf_agg, bb, buf_h);
        hin = buf_h;
    }

    hipMemsetAsync(pooled, 0, (size_t)GG * HD * sizeof(float), stream);
    hipMemsetAsync(cnt, 0, (size_t)GG * sizeof(float), stream);
    pool_accum<<<((int)N128 + 255) / 256, 256, 0, stream>>>(buf_h, batch, pooled);
    cnt_accum<<<(N_NODES + 255) / 256, 256, 0, stream>>>(batch, cnt);
    head<<<GG / 4, 256, 0, stream>>>(pooled, cnt, Wh, bh, out);
}

// Round 2
// 929.646 us; speedup vs baseline: 3.2906x; 3.2906x over previous
//
#include <hip/hip_runtime.h>
#include <math.h>

#define N_NODES 50000
#define N_EDGES 800000
#define HD 128          // H*D = 4*32
#define GG 1024
#define NEG_SLOPE 0.2f

// ---------------------------------------------------------------- GEMM (fp32)
// C[n,128] = A[n,K] @ W[K,128] + bias   (vector ALU; no fp32 MFMA on CDNA4)
template<int K>
__launch_bounds__(256)
__global__ void gemm_bias(const float* __restrict__ A, const float* __restrict__ W,
                          const float* __restrict__ bias, float* __restrict__ C, int n)
{
    constexpr int KC = 64;
    constexpr int NCHUNK = K / KC;
    __shared__ float Ws[KC * 128];        // 32 KB
    __shared__ float Xs[64 * (KC + 1)];   // 16.6 KB
    const int tid  = threadIdx.x;
    const int row0 = blockIdx.x * 64;
    const int cg   = (tid & 7) * 16;
    const int r0   = (tid >> 3) * 2;

    float acc[2][16];
    #pragma unroll
    for (int i = 0; i < 2; i++)
        #pragma unroll
        for (int j = 0; j < 16; j++) acc[i][j] = 0.f;

    for (int kc = 0; kc < NCHUNK; kc++) {
        const float4* wsrc = (const float4*)(W + (size_t)kc * KC * 128);
        float4* wdst = (float4*)Ws;
        #pragma unroll
        for (int i = 0; i < (KC * 32) / 256; i++)
            wdst[tid + i * 256] = wsrc[tid + i * 256];
        for (int i = tid; i < 64 * KC; i += 256) {
            int r = i >> 6;
            int k = i & 63;
            int row = row0 + r;
            Xs[r * (KC + 1) + k] = (row < n) ? A[(size_t)row * K + kc * KC + k] : 0.f;
        }
        __syncthreads();
        #pragma unroll 4
        for (int k = 0; k < KC; k++) {
            const float4 w0 = *(const float4*)&Ws[k * 128 + cg + 0];
            const float4 w1 = *(const float4*)&Ws[k * 128 + cg + 4];
            const float4 w2 = *(const float4*)&Ws[k * 128 + cg + 8];
            const float4 w3 = *(const float4*)&Ws[k * 128 + cg + 12];
            const float x0 = Xs[(r0 + 0) * (KC + 1) + k];
            const float x1 = Xs[(r0 + 1) * (KC + 1) + k];
            acc[0][0] += x0 * w0.x; acc[0][1] += x0 * w0.y; acc[0][2] += x0 * w0.z; acc[0][3] += x0 * w0.w;
            acc[0][4] += x0 * w1.x; acc[0][5] += x0 * w1.y; acc[0][6] += x0 * w1.z; acc[0][7] += x0 * w1.w;
            acc[0][8] += x0 * w2.x; acc[0][9] += x0 * w2.y; acc[0][10]+= x0 * w2.z; acc[0][11]+= x0 * w2.w;
            acc[0][12]+= x0 * w3.x; acc[0][13]+= x0 * w3.y; acc[0][14]+= x0 * w3.z; acc[0][15]+= x0 * w3.w;
            acc[1][0] += x1 * w0.x; acc[1][1] += x1 * w0.y; acc[1][2] += x1 * w0.z; acc[1][3] += x1 * w0.w;
            acc[1][4] += x1 * w1.x; acc[1][5] += x1 * w1.y; acc[1][6] += x1 * w1.z; acc[1][7] += x1 * w1.w;
            acc[1][8] += x1 * w2.x; acc[1][9] += x1 * w2.y; acc[1][10]+= x1 * w2.z; acc[1][11]+= x1 * w2.w;
            acc[1][12]+= x1 * w3.x; acc[1][13]+= x1 * w3.y; acc[1][14]+= x1 * w3.z; acc[1][15]+= x1 * w3.w;
        }
        __syncthreads();
    }

    const float4 b0 = *(const float4*)&bias[cg + 0];
    const float4 b1 = *(const float4*)&bias[cg + 4];
    const float4 b2 = *(const float4*)&bias[cg + 8];
    const float4 b3 = *(const float4*)&bias[cg + 12];
    #pragma unroll
    for (int i = 0; i < 2; i++) {
        int row = row0 + r0 + i;
        if (row < n) {
            float4* cp = (float4*)(C + (size_t)row * 128 + cg);
            cp[0] = make_float4(acc[i][0] + b0.x, acc[i][1] + b0.y, acc[i][2] + b0.z, acc[i][3] + b0.w);
            cp[1] = make_float4(acc[i][4] + b1.x, acc[i][5] + b1.y, acc[i][6] + b1.z, acc[i][7] + b1.w);
            cp[2] = make_float4(acc[i][8] + b2.x, acc[i][9] + b2.y, acc[i][10]+ b2.z, acc[i][11]+ b2.w);
            cp[3] = make_float4(acc[i][12]+ b3.x, acc[i][13]+ b3.y, acc[i][14]+ b3.z, acc[i][15]+ b3.w);
        }
    }
}

// ---------------------------------------------------------------- CSR build
__global__ void deg_hist(const int* __restrict__ dst, int* __restrict__ deg) {
    int e = blockIdx.x * 256 + threadIdx.x;
    if (e < N_EDGES) atomicAdd(&deg[dst[e]], 1);
}

// single-block exclusive scan over deg[N] -> rowptr[N+1], cursor[N]
__launch_bounds__(1024)
__global__ void scan_rowptr(const int* __restrict__ deg, int* __restrict__ rowptr,
                            int* __restrict__ cursor)
{
    __shared__ int s[1024];
    __shared__ int carry;
    const int tid = threadIdx.x;
    if (tid == 0) carry = 0;
    __syncthreads();
    for (int base = 0; base < N_NODES; base += 1024) {
        int i = base + tid;
        int v = (i < N_NODES) ? deg[i] : 0;
        s[tid] = v;
        __syncthreads();
        #pragma unroll
        for (int off = 1; off < 1024; off <<= 1) {
            int t = (tid >= off) ? s[tid - off] : 0;
            __syncthreads();
            s[tid] += t;
            __syncthreads();
        }
        int total = s[1023];
        int excl = s[tid] - v + carry;
        if (i < N_NODES) { rowptr[i] = excl; cursor[i] = excl; }
        __syncthreads();
        if (tid == 0) carry += total;
        __syncthreads();
    }
    if (tid == 0) rowptr[N_NODES] = carry;
}

__global__ void scatter_csr(const int* __restrict__ src, const int* __restrict__ dst,
                            int* __restrict__ cursor, int* __restrict__ csr_src)
{
    int e = blockIdx.x * 256 + threadIdx.x;
    if (e >= N_EDGES) return;
    int pos = atomicAdd(&cursor[dst[e]], 1);
    csr_src[pos] = src[e];
}

// ------------------------------------------------- fused per-node attention
// one wave per dst node; online softmax over its in-edges; fused bias + ELU.
__launch_bounds__(256)
__global__ void node_attn(const float* __restrict__ xl, const float* __restrict__ xr,
                          const int* __restrict__ rowptr, const int* __restrict__ csr_src,
                          const float* __restrict__ att, const float* __restrict__ bvec,
                          float* __restrict__ hout)
{
    const int node = (blockIdx.x * 256 + threadIdx.x) >> 6;
    const int lane = threadIdx.x & 63;
    if (node >= N_NODES) return;

    const float2 xrd = *(const float2*)(xr + (size_t)node * HD + lane * 2);
    const float2 aw  = *(const float2*)(att + lane * 2);
    const int beg = rowptr[node];
    const int end = rowptr[node + 1];

    float m = -__builtin_inff();
    float l = 0.f, ax = 0.f, ay = 0.f;

    // software pipeline: prefetch next src + next xl row
    int    s0 = (beg < end) ? csr_src[beg] : 0;
    float2 v0 = (beg < end) ? *(const float2*)(xl + (size_t)s0 * HD + lane * 2)
                            : make_float2(0.f, 0.f);
    for (int i = beg; i < end; i++) {
        float2 v1 = make_float2(0.f, 0.f);
        if (i + 1 < end) {
            int s1 = csr_src[i + 1];
            v1 = *(const float2*)(xl + (size_t)s1 * HD + lane * 2);
        }
        float t0 = v0.x + xrd.x; t0 = (t0 >= 0.f) ? t0 : NEG_SLOPE * t0;
        float t1 = v0.y + xrd.y; t1 = (t1 >= 0.f) ? t1 : NEG_SLOPE * t1;
        float p = t0 * aw.x + t1 * aw.y;
        p += __shfl_xor(p, 1);
        p += __shfl_xor(p, 2);
        p += __shfl_xor(p, 4);
        p += __shfl_xor(p, 8);      // all 16 lanes of the head group hold the score
        float mn = fmaxf(m, p);
        float sc = __expf(m - mn);  // first iter: exp(-inf) = 0
        float w  = __expf(p - mn);
        l  = l  * sc + w;
        ax = ax * sc + w * v0.x;
        ay = ay * sc + w * v0.y;
        m  = mn;
        v0 = v1;
    }

    const float inv = (l > 0.f) ? 1.f / l : 0.f;
    float o0 = ax * inv + bvec[lane * 2 + 0];
    float o1 = ay * inv + bvec[lane * 2 + 1];
    o0 = (o0 > 0.f) ? o0 : expm1f(o0);
    o1 = (o1 > 0.f) ? o1 : expm1f(o1);
    *(float2*)(hout + (size_t)node * HD + lane * 2) = make_float2(o0, o1);
}

// ---------------------------------------------------------------- pooling
__global__ void pool_accum(const float* __restrict__ h, const int* __restrict__ batch,
                           float* __restrict__ pooled)
{
    const int i = blockIdx.x * 256 + threadIdx.x;
    if (i >= N_NODES * HD) return;
    const int n = i >> 7;
    unsafeAtomicAdd(&pooled[(size_t)batch[n] * HD + (i & 127)], h[i]);
}

__global__ void cnt_accum(const int* __restrict__ batch, float* __restrict__ cnt)
{
    const int i = blockIdx.x * 256 + threadIdx.x;
    if (i < N_NODES) unsafeAtomicAdd(&cnt[batch[i]], 1.f);
}

__global__ void head(const float* __restrict__ pooled, const float* __restrict__ cnt,
                     const float* __restrict__ Wh, const float* __restrict__ bh,
                     float* __restrict__ out)
{
    const int g = (blockIdx.x * 256 + threadIdx.x) >> 6;
    const int lane = threadIdx.x & 63;
    if (g >= GG) return;
    const float2 p = *(const float2*)(pooled + (size_t)g * HD + lane * 2);
    const float2 w = *(const float2*)(Wh + lane * 2);
    float s = p.x * w.x + p.y * w.y;
    s += __shfl_xor(s, 1);
    s += __shfl_xor(s, 2);
    s += __shfl_xor(s, 4);
    s += __shfl_xor(s, 8);
    s += __shfl_xor(s, 16);
    s += __shfl_xor(s, 32);
    if (lane == 0) out[g] = s / fmaxf(cnt[g], 1.f) + bh[0];
}

// ---------------------------------------------------------------- launch
extern "C" void kernel_launch(void* const* d_in, const int* in_sizes, int n_in,
                              void* d_out, int out_size, void* d_ws, size_t ws_size,
                              hipStream_t stream)
{
    const float* x     = (const float*)d_in[0];
    const int*   edge  = (const int*)d_in[1];
    const int*   batch = (const int*)d_in[2];
    const int*   src   = edge;
    const int*   dst   = edge + N_EDGES;
    const float* Wh    = (const float*)d_in[21];
    const float* bh    = (const float*)d_in[22];
    float* out = (float*)d_out;

    const size_t N128 = (size_t)N_NODES * HD;
    float* ws      = (float*)d_ws;
    float* buf_h   = ws;                          // N*128
    float* buf_xl  = buf_h  + N128;               // N*128
    float* buf_xr  = buf_xl + N128;               // N*128
    float* pooled  = buf_xr + N128;               // G*128
    float* cnt     = pooled + (size_t)GG * HD;    // G
    int*   deg     = (int*)(cnt + GG);            // N
    int*   rowptr  = deg + N_NODES;               // N+1
    int*   cursor  = rowptr + N_NODES + 1;        // N
    int*   csr_src = cursor + N_NODES;            // E

    // ---- CSR build (once; edge structure identical across layers)
    hipMemsetAsync(deg, 0, (size_t)N_NODES * sizeof(int), stream);
    deg_hist<<<(N_EDGES + 255) / 256, 256, 0, stream>>>(dst, deg);
    scan_rowptr<<<1, 1024, 0, stream>>>(deg, rowptr, cursor);
    scatter_csr<<<(N_EDGES + 255) / 256, 256, 0, stream>>>(src, dst, cursor, csr_src);

    const float* hin = x;
    const int gemm_grid = (N_NODES + 63) / 64;
    const int attn_grid = (N_NODES + 3) / 4;

    for (int l = 0; l < 3; l++) {
        const float* Wl  = (const float*)d_in[3 + 6 * l];
        const float* bl  = (const float*)d_in[4 + 6 * l];
        const float* Wr  = (const float*)d_in[5 + 6 * l];
        const float* br  = (const float*)d_in[6 + 6 * l];
        const float* att = (const float*)d_in[7 + 6 * l];
        const float* bb  = (const float*)d_in[8 + 6 * l];

        if (l == 0) {
            gemm_bias<64><<<gemm_grid, 256, 0, stream>>>(hin, Wl, bl, buf_xl, N_NODES);
            gemm_bias<64><<<gemm_grid, 256, 0, stream>>>(hin, Wr, br, buf_xr, N_NODES);
        } else {
            gemm_bias<128><<<gemm_grid, 256, 0, stream>>>(hin, Wl, bl, buf_xl, N_NODES);
            gemm_bias<128><<<gemm_grid, 256, 0, stream>>>(hin, Wr, br, buf_xr, N_NODES);
        }
        node_attn<<<attn_grid, 256, 0, stream>>>(buf_xl, buf_xr, rowptr, csr_src,
                                                 att, bb, buf_h);
        hin = buf_h;
    }

    hipMemsetAsync(pooled, 0, (size_t)GG * HD * sizeof(float), stream);
    hipMemsetAsync(cnt, 0, (size_t)GG * sizeof(float), stream);
    pool_accum<<<((int)N128 + 255) / 256, 256, 0, stream>>>(buf_h, batch, pooled);
    cnt_accum<<<(N_NODES + 255) / 256, 256, 0, stream>>>(batch, cnt);
    head<<<GG / 4, 256, 0, stream>>>(pooled, cnt, Wh, bh, out);
}

// Round 3
// 626.850 us; speedup vs baseline: 4.8801x; 1.4830x over previous
//
#include <hip/hip_runtime.h>
#include <math.h>

#define N_NODES 50000
#define N_EDGES 800000
#define HD 128          // H*D = 4*32
#define GG 1024
#define NEG_SLOPE 0.2f
#define SCAN_B 1024
#define NB ((N_NODES + SCAN_B - 1) / SCAN_B)   // 49

// ------------------------------------------------------------- fused dual GEMM
// Cl[n,128] = A[n,K]@Wl + bl ; Cr[n,128] = A[n,K]@Wr + br   (fp32 VALU)
// block tile: 64 rows x 256 cols (128 Wl | 128 Wr). thread: 4 rows x 16 cols.
// W staged with 20-word chunk skew (<=2-way LDS banks); Xs stride 33 (<=2-way).
template<int K>
__launch_bounds__(256)
__global__ void gemm_dual(const float* __restrict__ A,
                          const float* __restrict__ Wl, const float* __restrict__ bl,
                          const float* __restrict__ Wr, const float* __restrict__ br,
                          float* __restrict__ Cl, float* __restrict__ Cr, int n)
{
    constexpr int KC = 32;
    constexpr int NCH = K / KC;
    constexpr int WROW = 320;            // 16 chunks * 20 words (skewed 256-col row)
    __shared__ float Ws[KC * WROW];      // 40 KB
    __shared__ float Xs[64 * 33];        // 8.25 KB
    const int tid  = threadIdx.x;
    const int row0 = blockIdx.x * 64;
    const int cgi  = tid & 15;           // col-group (16 cols of 256)
    const int r0   = (tid >> 4) * 4;     // 4 rows

    float acc[4][16];
    #pragma unroll
    for (int i = 0; i < 4; i++)
        #pragma unroll
        for (int j = 0; j < 16; j++) acc[i][j] = 0.f;

    for (int ch = 0; ch < NCH; ch++) {
        const int kbase = ch * KC;
        // ---- stage W (both matrices): 2048 float4, 8/thread, skewed dst
        #pragma unroll
        for (int i = 0; i < 8; i++) {
            int f = tid + i * 256;       // 0..2047
            int k = f >> 6;              // 0..31
            int q = f & 63;              // float4 idx in 256-col row
            const float* sp = (q < 32)
                ? (Wl + (size_t)(kbase + k) * 128 + q * 4)
                : (Wr + (size_t)(kbase + k) * 128 + (q - 32) * 4);
            float4 w = *(const float4*)sp;
            *(float4*)&Ws[k * WROW + (q >> 2) * 20 + (q & 3) * 4] = w;
        }
        // ---- stage X: 512 float4, 2/thread, stride-33 rows
        #pragma unroll
        for (int i = 0; i < 2; i++) {
            int f = tid + i * 256;       // 0..511
            int r = f >> 3;
            int kg = f & 7;
            int row = row0 + r;
            float4 xv = (row < n) ? *(const float4*)(A + (size_t)row * K + kbase + kg * 4)
                                  : make_float4(0.f, 0.f, 0.f, 0.f);
            float* xp = &Xs[r * 33 + kg * 4];
            xp[0] = xv.x; xp[1] = xv.y; xp[2] = xv.z; xp[3] = xv.w;
        }
        __syncthreads();
        #pragma unroll 8
        for (int k = 0; k < KC; k++) {
            const float4 w0 = *(const float4*)&Ws[k * WROW + cgi * 20 + 0];
            const float4 w1 = *(const float4*)&Ws[k * WROW + cgi * 20 + 4];
            const float4 w2 = *(const float4*)&Ws[k * WROW + cgi * 20 + 8];
            const float4 w3 = *(const float4*)&Ws[k * WROW + cgi * 20 + 12];
            const float x0 = Xs[(r0 + 0) * 33 + k];
            const float x1 = Xs[(r0 + 1) * 33 + k];
            const float x2 = Xs[(r0 + 2) * 33 + k];
            const float x3 = Xs[(r0 + 3) * 33 + k];
            #define ROWFMA(i, xi) \
                acc[i][0] += xi * w0.x; acc[i][1] += xi * w0.y; acc[i][2] += xi * w0.z; acc[i][3] += xi * w0.w; \
                acc[i][4] += xi * w1.x; acc[i][5] += xi * w1.y; acc[i][6] += xi * w1.z; acc[i][7] += xi * w1.w; \
                acc[i][8] += xi * w2.x; acc[i][9] += xi * w2.y; acc[i][10]+= xi * w2.z; acc[i][11]+= xi * w2.w; \
                acc[i][12]+= xi * w3.x; acc[i][13]+= xi * w3.y; acc[i][14]+= xi * w3.z; acc[i][15]+= xi * w3.w;
            ROWFMA(0, x0) ROWFMA(1, x1) ROWFMA(2, x2) ROWFMA(3, x3)
            #undef ROWFMA
        }
        __syncthreads();
    }

    const bool isL = (cgi < 8);
    const int c0 = (cgi & 7) * 16;
    const float* bias = isL ? bl : br;
    float* C = isL ? Cl : Cr;
    const float4 b0 = *(const float4*)&bias[c0 + 0];
    const float4 b1 = *(const float4*)&bias[c0 + 4];
    const float4 b2 = *(const float4*)&bias[c0 + 8];
    const float4 b3 = *(const float4*)&bias[c0 + 12];
    #pragma unroll
    for (int i = 0; i < 4; i++) {
        int row = row0 + r0 + i;
        if (row < n) {
            float4* cp = (float4*)(C + (size_t)row * 128 + c0);
            cp[0] = make_float4(acc[i][0] + b0.x, acc[i][1] + b0.y, acc[i][2] + b0.z, acc[i][3] + b0.w);
            cp[1] = make_float4(acc[i][4] + b1.x, acc[i][5] + b1.y, acc[i][6] + b1.z, acc[i][7] + b1.w);
            cp[2] = make_float4(acc[i][8] + b2.x, acc[i][9] + b2.y, acc[i][10]+ b2.z, acc[i][11]+ b2.w);
            cp[3] = make_float4(acc[i][12]+ b3.x, acc[i][13]+ b3.y, acc[i][14]+ b3.z, acc[i][15]+ b3.w);
        }
    }
}

// ---------------------------------------------------------------- CSR build
__global__ void deg_hist(const int* __restrict__ dst, int* __restrict__ deg) {
    int e = blockIdx.x * 256 + threadIdx.x;
    if (e < N_EDGES) atomicAdd(&deg[dst[e]], 1);
}

__launch_bounds__(SCAN_B)
__global__ void scan_block(const int* __restrict__ deg, int* __restrict__ rowptr,
                           int* __restrict__ btot)
{
    __shared__ int s[SCAN_B];
    const int tid = threadIdx.x;
    const int i = blockIdx.x * SCAN_B + tid;
    int v = (i < N_NODES) ? deg[i] : 0;
    s[tid] = v;
    __syncthreads();
    for (int off = 1; off < SCAN_B; off <<= 1) {
        int t = (tid >= off) ? s[tid - off] : 0;
        __syncthreads();
        s[tid] += t;
        __syncthreads();
    }
    if (i < N_NODES) rowptr[i] = s[tid] - v;   // local exclusive
    if (tid == SCAN_B - 1) btot[blockIdx.x] = s[SCAN_B - 1];
}

__global__ void scan_btot(const int* __restrict__ btot, int* __restrict__ boff) {
    if (threadIdx.x == 0) {
        int a = 0;
        for (int b = 0; b < NB; b++) { boff[b] = a; a += btot[b]; }
        boff[NB] = a;
    }
}

__global__ void scan_add(const int* __restrict__ boff, int* __restrict__ rowptr,
                         int* __restrict__ cursor)
{
    int i = blockIdx.x * 256 + threadIdx.x;
    if (i < N_NODES) {
        int r = rowptr[i] + boff[i >> 10];
        rowptr[i] = r;
        cursor[i] = r;
    }
    if (i == N_NODES) rowptr[N_NODES] = boff[NB];
}

__global__ void scatter_csr(const int* __restrict__ src, const int* __restrict__ dst,
                            int* __restrict__ cursor, int* __restrict__ csr_src)
{
    int e = blockIdx.x * 256 + threadIdx.x;
    if (e >= N_EDGES) return;
    int pos = atomicAdd(&cursor[dst[e]], 1);
    csr_src[pos] = src[e];
}

// ------------------------------------------------- fused per-node attention
// one wave per dst node, TWO edges in flight (lanes 0-31 / 32-63).
// within an edge-half: 4 heads x 8 lanes x float4; 3-shuffle score reduce.
__launch_bounds__(256)
__global__ void node_attn(const float* __restrict__ xl, const float* __restrict__ xr,
                          const int* __restrict__ rowptr, const int* __restrict__ csr_src,
                          const float* __restrict__ att, const float* __restrict__ bvec,
                          float* __restrict__ hout)
{
    const int node = (blockIdx.x * 256 + threadIdx.x) >> 6;
    const int lane = threadIdx.x & 63;
    if (node >= N_NODES) return;
    const int half = lane >> 5;          // edge slot 0/1
    const int li   = lane & 31;          // dim slot: covers cols li*4..li*4+3

    const float4 xrd = *(const float4*)(xr + (size_t)node * HD + li * 4);
    const float4 aw  = *(const float4*)(att + li * 4);
    const int beg = rowptr[node];
    const int end = rowptr[node + 1];

    float m = -1e30f, l = 0.f;
    float4 acc = make_float4(0.f, 0.f, 0.f, 0.f);

    // prefetch first edge pair
    int e0 = beg + half;
    int s0 = (e0 < end) ? csr_src[e0] : 0;
    float4 v = *(const float4*)(xl + (size_t)s0 * HD + li * 4);

    for (int base = beg; base < end; base += 2) {
        const bool valid = (base + half) < end;
        // prefetch next pair (wave-uniform branch)
        float4 vn = v;
        if (base + 2 < end) {
            int e2 = base + 2 + half;
            int s2 = (e2 < end) ? csr_src[e2] : 0;
            vn = *(const float4*)(xl + (size_t)s2 * HD + li * 4);
        }
        float t0 = v.x + xrd.x; t0 = (t0 >= 0.f) ? t0 : NEG_SLOPE * t0;
        float t1 = v.y + xrd.y; t1 = (t1 >= 0.f) ? t1 : NEG_SLOPE * t1;
        float t2 = v.z + xrd.z; t2 = (t2 >= 0.f) ? t2 : NEG_SLOPE * t2;
        float t3 = v.w + xrd.w; t3 = (t3 >= 0.f) ? t3 : NEG_SLOPE * t3;
        float p = t0 * aw.x + t1 * aw.y + t2 * aw.z + t3 * aw.w;
        p += __shfl_xor(p, 1);
        p += __shfl_xor(p, 2);
        p += __shfl_xor(p, 4);           // head score, replicated in 8-lane group
        const float mn = valid ? fmaxf(m, p) : m;
        const float w  = valid ? __expf(p - mn) : 0.f;
        const float sc = __expf(m - mn); // m==mn when invalid -> 1
        l = l * sc + w;
        acc.x = acc.x * sc + w * v.x;
        acc.y = acc.y * sc + w * v.y;
        acc.z = acc.z * sc + w * v.z;
        acc.w = acc.w * sc + w * v.w;
        m = mn;
        v = vn;
    }

    // merge the two half-wave softmax states
    const float mo = __shfl_xor(m, 32);
    const float lo = __shfl_xor(l, 32);
    float4 ao;
    ao.x = __shfl_xor(acc.x, 32);
    ao.y = __shfl_xor(acc.y, 32);
    ao.z = __shfl_xor(acc.z, 32);
    ao.w = __shfl_xor(acc.w, 32);
    const float mm = fmaxf(m, mo);
    const float e1 = __expf(m - mm);     // both -1e30 -> exp(0)=1, l==0 anyway
    const float e2 = __expf(mo - mm);
    const float ll = l * e1 + lo * e2;
    const float inv = (ll > 0.f) ? 1.f / ll : 0.f;
    const float4 bb = *(const float4*)(bvec + li * 4);
    float o0 = (acc.x * e1 + ao.x * e2) * inv + bb.x;
    float o1 = (acc.y * e1 + ao.y * e2) * inv + bb.y;
    float o2 = (acc.z * e1 + ao.z * e2) * inv + bb.z;
    float o3 = (acc.w * e1 + ao.w * e2) * inv + bb.w;
    o0 = (o0 > 0.f) ? o0 : expm1f(o0);
    o1 = (o1 > 0.f) ? o1 : expm1f(o1);
    o2 = (o2 > 0.f) ? o2 : expm1f(o2);
    o3 = (o3 > 0.f) ? o3 : expm1f(o3);
    if (half == 0)
        *(float4*)(hout + (size_t)node * HD + li * 4) = make_float4(o0, o1, o2, o3);
}

// ---------------------------------------------------------------- pooling
__global__ void pool_accum(const float* __restrict__ h, const int* __restrict__ batch,
                           float* __restrict__ pooled)
{
    const int i = blockIdx.x * 256 + threadIdx.x;
    if (i >= N_NODES * HD) return;
    const int n = i >> 7;
    unsafeAtomicAdd(&pooled[(size_t)batch[n] * HD + (i & 127)], h[i]);
}

__global__ void cnt_accum(const int* __restrict__ batch, float* __restrict__ cnt)
{
    const int i = blockIdx.x * 256 + threadIdx.x;
    if (i < N_NODES) unsafeAtomicAdd(&cnt[batch[i]], 1.f);
}

__global__ void head(const float* __restrict__ pooled, const float* __restrict__ cnt,
                     const float* __restrict__ Wh, const float* __restrict__ bh,
                     float* __restrict__ out)
{
    const int g = (blockIdx.x * 256 + threadIdx.x) >> 6;
    const int lane = threadIdx.x & 63;
    if (g >= GG) return;
    const float2 p = *(const float2*)(pooled + (size_t)g * HD + lane * 2);
    const float2 w = *(const float2*)(Wh + lane * 2);
    float s = p.x * w.x + p.y * w.y;
    s += __shfl_xor(s, 1);
    s += __shfl_xor(s, 2);
    s += __shfl_xor(s, 4);
    s += __shfl_xor(s, 8);
    s += __shfl_xor(s, 16);
    s += __shfl_xor(s, 32);
    if (lane == 0) out[g] = s / fmaxf(cnt[g], 1.f) + bh[0];
}

// ---------------------------------------------------------------- launch
extern "C" void kernel_launch(void* const* d_in, const int* in_sizes, int n_in,
                              void* d_out, int out_size, void* d_ws, size_t ws_size,
                              hipStream_t stream)
{
    const float* x     = (const float*)d_in[0];
    const int*   edge  = (const int*)d_in[1];
    const int*   batch = (const int*)d_in[2];
    const int*   src   = edge;
    const int*   dst   = edge + N_EDGES;
    const float* Wh    = (const float*)d_in[21];
    const float* bh    = (const float*)d_in[22];
    float* out = (float*)d_out;

    const size_t N128 = (size_t)N_NODES * HD;
    float* ws      = (float*)d_ws;
    float* buf_h   = ws;                          // N*128
    float* buf_xl  = buf_h  + N128;               // N*128
    float* buf_xr  = buf_xl + N128;               // N*128
    float* pooled  = buf_xr + N128;               // G*128
    float* cnt     = pooled + (size_t)GG * HD;    // G
    int*   deg     = (int*)(cnt + GG);            // N
    int*   rowptr  = deg + N_NODES;               // N+1
    int*   cursor  = rowptr + N_NODES + 1;        // N
    int*   csr_src = cursor + N_NODES;            // E
    int*   btot    = csr_src + N_EDGES;           // NB
    int*   boff    = btot + NB;                   // NB+1

    // ---- CSR build (edge structure is layer-invariant)
    hipMemsetAsync(deg, 0, (size_t)N_NODES * sizeof(int), stream);
    deg_hist<<<(N_EDGES + 255) / 256, 256, 0, stream>>>(dst, deg);
    scan_block<<<NB, SCAN_B, 0, stream>>>(deg, rowptr, btot);
    scan_btot<<<1, 64, 0, stream>>>(btot, boff);
    scan_add<<<(N_NODES + 256) / 256, 256, 0, stream>>>(boff, rowptr, cursor);
    scatter_csr<<<(N_EDGES + 255) / 256, 256, 0, stream>>>(src, dst, cursor, csr_src);

    const float* hin = x;
    const int gemm_grid = (N_NODES + 63) / 64;
    const int attn_grid = (N_NODES + 3) / 4;

    for (int l = 0; l < 3; l++) {
        const float* Wl  = (const float*)d_in[3 + 6 * l];
        const float* bl  = (const float*)d_in[4 + 6 * l];
        const float* Wr  = (const float*)d_in[5 + 6 * l];
        const float* br  = (const float*)d_in[6 + 6 * l];
        const float* att = (const float*)d_in[7 + 6 * l];
        const float* bb  = (const float*)d_in[8 + 6 * l];

        if (l == 0)
            gemm_dual<64><<<gemm_grid, 256, 0, stream>>>(hin, Wl, bl, Wr, br,
                                                         buf_xl, buf_xr, N_NODES);
        else
            gemm_dual<128><<<gemm_grid, 256, 0, stream>>>(hin, Wl, bl, Wr, br,
                                                          buf_xl, buf_xr, N_NODES);
        node_attn<<<attn_grid, 256, 0, stream>>>(buf_xl, buf_xr, rowptr, csr_src,
                                                 att, bb, buf_h);
        hin = buf_h;
    }

    hipMemsetAsync(pooled, 0, (size_t)GG * HD * sizeof(float), stream);
    hipMemsetAsync(cnt, 0, (size_t)GG * sizeof(float), stream);
    pool_accum<<<((int)N128 + 255) / 256, 256, 0, stream>>>(buf_h, batch, pooled);
    cnt_accum<<<(N_NODES + 255) / 256, 256, 0, stream>>>(batch, cnt);
    head<<<GG / 4, 256, 0, stream>>>(pooled, cnt, Wh, bh, out);
}

// Round 4
// 525.826 us; speedup vs baseline: 5.8176x; 1.1921x over previous
//
#include <hip/hip_runtime.h>
#include <math.h>

#define N_NODES 50000
#define N_EDGES 800000
#define HD 128          // H*D = 4*32
#define GG 1024
#define NEG_SLOPE 0.2f
#define SCAN_B 1024
#define NB ((N_NODES + SCAN_B - 1) / SCAN_B)   // 49

typedef __attribute__((ext_vector_type(8))) short bf16x8;
typedef __attribute__((ext_vector_type(4))) float f32x4;

__device__ __forceinline__ unsigned short f2bf(float v) {
    unsigned u = __float_as_uint(v);
    u += 0x7fff + ((u >> 16) & 1);       // round-to-nearest-even
    return (unsigned short)(u >> 16);
}
__device__ __forceinline__ float bf2f(unsigned short s) {
    return __uint_as_float((unsigned)s << 16);
}

// --------------------------------------------------- split-bf16 conversions
__global__ void convert_x(const float* __restrict__ x, unsigned short* __restrict__ Xh,
                          unsigned short* __restrict__ Xl, int total)
{
    int i = blockIdx.x * 256 + threadIdx.x;
    if (i >= total) return;
    float v = x[i];
    unsigned short hi = f2bf(v);
    unsigned short lo = f2bf(v - bf2f(hi));   // residual is exact in fp32
    Xh[i] = hi; Xl[i] = lo;
}

// W (K x 128) pair -> Wt (256 x K) transposed, split hi/lo. rows 0..127 = Wl cols.
__global__ void convert_w(const float* __restrict__ Wl, const float* __restrict__ Wr,
                          unsigned short* __restrict__ Wth, unsigned short* __restrict__ Wtl,
                          int K)
{
    int t = blockIdx.x * 256 + threadIdx.x;
    if (t >= 256 * K) return;
    int c = t / K, k = t - c * K;
    float v = (c < 128) ? Wl[(size_t)k * 128 + c] : Wr[(size_t)k * 128 + (c - 128)];
    unsigned short hi = f2bf(v);
    unsigned short lo = f2bf(v - bf2f(hi));
    Wth[t] = hi; Wtl[t] = lo;
}

// --------------------------------------------------- MFMA split-bf16 dual GEMM
// Cl[n,128]=X@Wl+bl ; Cr[n,128]=X@Wr+br. X given as bf16 hi/lo row-major [n][K],
// W given transposed [256][K] bf16 hi/lo. Block: 64 rows x 256 cols, 4 waves,
// wave-tile 64x64 (4x4 of 16x16x32), 3 MFMA per tile-pair (hh, hl, lh).
template<int K>
__launch_bounds__(256)
__global__ void gemm_mfma(const unsigned short* __restrict__ Xh, const unsigned short* __restrict__ Xl,
                          const unsigned short* __restrict__ Wth, const unsigned short* __restrict__ Wtl,
                          const float* __restrict__ bl, const float* __restrict__ br,
                          float* __restrict__ Cl, float* __restrict__ Cr, int n)
{
    constexpr int KC = 32;
    constexpr int NCH = K / KC;
    constexpr int XR = 40;                     // LDS row stride (elems): 80 B -> 2-way max
    __shared__ unsigned short XsH[64 * XR], XsL[64 * XR];     // 5.12 KB each
    __shared__ unsigned short WsH[256 * XR], WsL[256 * XR];   // 20.5 KB each
    const int tid  = threadIdx.x;
    const int wave = tid >> 6;
    const int lane = tid & 63;
    const int quad = lane >> 4;
    const int l15  = lane & 15;
    const int row0 = blockIdx.x * 64;

    f32x4 acc[4][4];                           // [mt][nt]
    #pragma unroll
    for (int i = 0; i < 4; i++)
        #pragma unroll
        for (int j = 0; j < 4; j++) acc[i][j] = (f32x4){0.f, 0.f, 0.f, 0.f};

    for (int ch = 0; ch < NCH; ch++) {
        const int k0 = ch * KC;
        // stage X chunk: 64 rows x 32 k (1 uint4 per thread per buffer)
        {
            const int r = tid >> 2, seg = tid & 3;
            const int row = row0 + r;
            const size_t go = (size_t)row * K + k0 + seg * 8;
            uint4 vh = make_uint4(0, 0, 0, 0), vl = make_uint4(0, 0, 0, 0);
            if (row < n) { vh = *(const uint4*)(Xh + go); vl = *(const uint4*)(Xl + go); }
            *(uint4*)&XsH[r * XR + seg * 8] = vh;
            *(uint4*)&XsL[r * XR + seg * 8] = vl;
        }
        // stage W chunk: 256 rows x 32 k (4 uint4 per thread per buffer)
        #pragma unroll
        for (int i = 0; i < 4; i++) {
            const int f = tid + i * 256;
            const int wr = f >> 2, seg = f & 3;
            const size_t go = (size_t)wr * K + k0 + seg * 8;
            *(uint4*)&WsH[wr * XR + seg * 8] = *(const uint4*)(Wth + go);
            *(uint4*)&WsL[wr * XR + seg * 8] = *(const uint4*)(Wtl + go);
        }
        __syncthreads();

        bf16x8 ah[4], al[4];
        #pragma unroll
        for (int mt = 0; mt < 4; mt++) {
            ah[mt] = *(const bf16x8*)&XsH[(mt * 16 + l15) * XR + quad * 8];
            al[mt] = *(const bf16x8*)&XsL[(mt * 16 + l15) * XR + quad * 8];
        }
        #pragma unroll
        for (int nt = 0; nt < 4; nt++) {
            const int wr = wave * 64 + nt * 16 + l15;
            const bf16x8 bh = *(const bf16x8*)&WsH[wr * XR + quad * 8];
            const bf16x8 bo = *(const bf16x8*)&WsL[wr * XR + quad * 8];
            #pragma unroll
            for (int mt = 0; mt < 4; mt++) {
                acc[mt][nt] = __builtin_amdgcn_mfma_f32_16x16x32_bf16(ah[mt], bh, acc[mt][nt], 0, 0, 0);
                acc[mt][nt] = __builtin_amdgcn_mfma_f32_16x16x32_bf16(ah[mt], bo, acc[mt][nt], 0, 0, 0);
                acc[mt][nt] = __builtin_amdgcn_mfma_f32_16x16x32_bf16(al[mt], bh, acc[mt][nt], 0, 0, 0);
            }
        }
        __syncthreads();
    }

    // epilogue: C/D layout col=lane&15, row=quad*4+reg [m89-verified]
    const bool isL = (wave < 2);
    const int colbase = (wave & 1) * 64;
    const float* bias = isL ? bl : br;
    float* C = isL ? Cl : Cr;
    #pragma unroll
    for (int nt = 0; nt < 4; nt++) {
        const float bv = bias[colbase + nt * 16 + l15];
        #pragma unroll
        for (int mt = 0; mt < 4; mt++) {
            #pragma unroll
            for (int r = 0; r < 4; r++) {
                const int row = row0 + mt * 16 + quad * 4 + r;
                if (row < n)
                    C[(size_t)row * 128 + colbase + nt * 16 + l15] = acc[mt][nt][r] + bv;
            }
        }
    }
}

// ---------------------------------------------------------------- CSR build
__global__ void deg_hist(const int* __restrict__ dst, int* __restrict__ deg) {
    int e = blockIdx.x * 256 + threadIdx.x;
    if (e < N_EDGES) atomicAdd(&deg[dst[e]], 1);
}

__launch_bounds__(SCAN_B)
__global__ void scan_block(const int* __restrict__ deg, int* __restrict__ rowptr,
                           int* __restrict__ btot)
{
    __shared__ int s[SCAN_B];
    const int tid = threadIdx.x;
    const int i = blockIdx.x * SCAN_B + tid;
    int v = (i < N_NODES) ? deg[i] : 0;
    s[tid] = v;
    __syncthreads();
    for (int off = 1; off < SCAN_B; off <<= 1) {
        int t = (tid >= off) ? s[tid - off] : 0;
        __syncthreads();
        s[tid] += t;
        __syncthreads();
    }
    if (i < N_NODES) rowptr[i] = s[tid] - v;
    if (tid == SCAN_B - 1) btot[blockIdx.x] = s[SCAN_B - 1];
}

__global__ void scan_btot(const int* __restrict__ btot, int* __restrict__ boff) {
    if (threadIdx.x == 0) {
        int a = 0;
        for (int b = 0; b < NB; b++) { boff[b] = a; a += btot[b]; }
        boff[NB] = a;
    }
}

__global__ void scan_add(const int* __restrict__ boff, int* __restrict__ rowptr,
                         int* __restrict__ cursor)
{
    int i = blockIdx.x * 256 + threadIdx.x;
    if (i < N_NODES) {
        int r = rowptr[i] + boff[i >> 10];
        rowptr[i] = r;
        cursor[i] = r;
    }
    if (i == N_NODES) rowptr[N_NODES] = boff[NB];
}

__global__ void scatter_csr(const int* __restrict__ src, const int* __restrict__ dst,
                            int* __restrict__ cursor, int* __restrict__ csr_src)
{
    int e = blockIdx.x * 256 + threadIdx.x;
    if (e >= N_EDGES) return;
    int pos = atomicAdd(&cursor[dst[e]], 1);
    csr_src[pos] = src[e];
}

// graph boundaries from sorted batch: gptr[G+1]
__global__ void build_gptr(const int* __restrict__ batch, int* __restrict__ gptr) {
    int i = blockIdx.x * 256 + threadIdx.x;
    if (i > N_NODES) return;
    if (i == 0) {
        for (int g = 0; g <= batch[0]; g++) gptr[g] = 0;
    } else if (i == N_NODES) {
        for (int g = batch[N_NODES - 1] + 1; g <= GG; g++) gptr[g] = N_NODES;
    } else {
        int b0 = batch[i - 1], b1 = batch[i];
        for (int g = b0 + 1; g <= b1; g++) gptr[g] = i;
    }
}

// ------------------------------------------------- fused per-node attention
// one wave per dst node, TWO edges in flight; epilogue emits bf16 hi/lo splits.
__launch_bounds__(256)
__global__ void node_attn(const float* __restrict__ xl, const float* __restrict__ xr,
                          const int* __restrict__ rowptr, const int* __restrict__ csr_src,
                          const float* __restrict__ att, const float* __restrict__ bvec,
                          unsigned short* __restrict__ Hh, unsigned short* __restrict__ Hl)
{
    const int node = (blockIdx.x * 256 + threadIdx.x) >> 6;
    const int lane = threadIdx.x & 63;
    if (node >= N_NODES) return;
    const int half = lane >> 5;
    const int li   = lane & 31;

    const float4 xrd = *(const float4*)(xr + (size_t)node * HD + li * 4);
    const float4 aw  = *(const float4*)(att + li * 4);
    const int beg = rowptr[node];
    const int end = rowptr[node + 1];

    float m = -1e30f, l = 0.f;
    float4 acc = make_float4(0.f, 0.f, 0.f, 0.f);

    int e0 = beg + half;
    int s0 = (e0 < end) ? csr_src[e0] : 0;
    float4 v = *(const float4*)(xl + (size_t)s0 * HD + li * 4);

    for (int base = beg; base < end; base += 2) {
        const bool valid = (base + half) < end;
        float4 vn = v;
        if (base + 2 < end) {
            int e2 = base + 2 + half;
            int s2 = (e2 < end) ? csr_src[e2] : 0;
            vn = *(const float4*)(xl + (size_t)s2 * HD + li * 4);
        }
        float t0 = v.x + xrd.x; t0 = (t0 >= 0.f) ? t0 : NEG_SLOPE * t0;
        float t1 = v.y + xrd.y; t1 = (t1 >= 0.f) ? t1 : NEG_SLOPE * t1;
        float t2 = v.z + xrd.z; t2 = (t2 >= 0.f) ? t2 : NEG_SLOPE * t2;
        float t3 = v.w + xrd.w; t3 = (t3 >= 0.f) ? t3 : NEG_SLOPE * t3;
        float p = t0 * aw.x + t1 * aw.y + t2 * aw.z + t3 * aw.w;
        p += __shfl_xor(p, 1);
        p += __shfl_xor(p, 2);
        p += __shfl_xor(p, 4);
        const float mn = valid ? fmaxf(m, p) : m;
        const float w  = valid ? __expf(p - mn) : 0.f;
        const float sc = __expf(m - mn);
        l = l * sc + w;
        acc.x = acc.x * sc + w * v.x;
        acc.y = acc.y * sc + w * v.y;
        acc.z = acc.z * sc + w * v.z;
        acc.w = acc.w * sc + w * v.w;
        m = mn;
        v = vn;
    }

    const float mo = __shfl_xor(m, 32);
    const float lo = __shfl_xor(l, 32);
    float4 ao;
    ao.x = __shfl_xor(acc.x, 32);
    ao.y = __shfl_xor(acc.y, 32);
    ao.z = __shfl_xor(acc.z, 32);
    ao.w = __shfl_xor(acc.w, 32);
    const float mm = fmaxf(m, mo);
    const float e1 = __expf(m - mm);
    const float e2 = __expf(mo - mm);
    const float ll = l * e1 + lo * e2;
    const float inv = (ll > 0.f) ? 1.f / ll : 0.f;
    const float4 bb = *(const float4*)(bvec + li * 4);
    float o0 = (acc.x * e1 + ao.x * e2) * inv + bb.x;
    float o1 = (acc.y * e1 + ao.y * e2) * inv + bb.y;
    float o2 = (acc.z * e1 + ao.z * e2) * inv + bb.z;
    float o3 = (acc.w * e1 + ao.w * e2) * inv + bb.w;
    o0 = (o0 > 0.f) ? o0 : expm1f(o0);
    o1 = (o1 > 0.f) ? o1 : expm1f(o1);
    o2 = (o2 > 0.f) ? o2 : expm1f(o2);
    o3 = (o3 > 0.f) ? o3 : expm1f(o3);
    if (half == 0) {
        unsigned short h0 = f2bf(o0), h1 = f2bf(o1), h2 = f2bf(o2), h3 = f2bf(o3);
        unsigned short l0 = f2bf(o0 - bf2f(h0)), l1 = f2bf(o1 - bf2f(h1));
        unsigned short l2 = f2bf(o2 - bf2f(h2)), l3 = f2bf(o3 - bf2f(h3));
        *(ushort4*)(Hh + (size_t)node * HD + li * 4) = make_ushort4(h0, h1, h2, h3);
        *(ushort4*)(Hl + (size_t)node * HD + li * 4) = make_ushort4(l0, l1, l2, l3);
    }
}

// ------------------------------------------ fused mean-pool + linear head
// one wave per graph (batch sorted): sums h rows, dots with Wh, scales by 1/cnt.
__launch_bounds__(256)
__global__ void pool_head(const unsigned short* __restrict__ Hh, const unsigned short* __restrict__ Hl,
                          const int* __restrict__ gptr, const float* __restrict__ Wh,
                          const float* __restrict__ bh, float* __restrict__ out)
{
    const int g = (blockIdx.x * 256 + threadIdx.x) >> 6;
    const int lane = threadIdx.x & 63;
    if (g >= GG) return;
    const int b0 = gptr[g], b1 = gptr[g + 1];
    const float2 w = *(const float2*)(Wh + lane * 2);
    float sx = 0.f, sy = 0.f;
    for (int i = b0; i < b1; i++) {
        const unsigned vh = *(const unsigned*)(Hh + (size_t)i * HD + lane * 2);
        const unsigned vl = *(const unsigned*)(Hl + (size_t)i * HD + lane * 2);
        sx += bf2f((unsigned short)(vh & 0xffff)) + bf2f((unsigned short)(vl & 0xffff));
        sy += bf2f((unsigned short)(vh >> 16))    + bf2f((unsigned short)(vl >> 16));
    }
    float d = sx * w.x + sy * w.y;
    d += __shfl_xor(d, 1);
    d += __shfl_xor(d, 2);
    d += __shfl_xor(d, 4);
    d += __shfl_xor(d, 8);
    d += __shfl_xor(d, 16);
    d += __shfl_xor(d, 32);
    if (lane == 0) out[g] = d / fmaxf((float)(b1 - b0), 1.f) + bh[0];
}

// ---------------------------------------------------------------- launch
extern "C" void kernel_launch(void* const* d_in, const int* in_sizes, int n_in,
                              void* d_out, int out_size, void* d_ws, size_t ws_size,
                              hipStream_t stream)
{
    const float* x     = (const float*)d_in[0];
    const int*   edge  = (const int*)d_in[1];
    const int*   batch = (const int*)d_in[2];
    const int*   src   = edge;
    const int*   dst   = edge + N_EDGES;
    const float* Wh    = (const float*)d_in[21];
    const float* bh    = (const float*)d_in[22];
    float* out = (float*)d_out;

    const size_t N128 = (size_t)N_NODES * HD;
    float* buf_xl = (float*)d_ws;                       // N*128 f32
    float* buf_xr = buf_xl + N128;                      // N*128 f32
    unsigned short* Xh  = (unsigned short*)(buf_xr + N128);   // N*128 bf16
    unsigned short* Xl_ = Xh + N128;                    // N*128 bf16
    unsigned short* Wth = Xl_ + N128;                   // 3 * 256*128 bf16
    unsigned short* Wtl = Wth + 3 * 256 * 128;          // 3 * 256*128 bf16
    int* deg     = (int*)(Wtl + 3 * 256 * 128);         // N
    int* rowptr  = deg + N_NODES;                       // N+1
    int* cursor  = rowptr + N_NODES + 1;                // N
    int* csr_src = cursor + N_NODES;                    // E
    int* btot    = csr_src + N_EDGES;                   // NB
    int* boff    = btot + NB;                           // NB+1
    int* gptr    = boff + NB + 1;                       // G+1

    // ---- CSR + graph-boundary build (layer-invariant)
    hipMemsetAsync(deg, 0, (size_t)N_NODES * sizeof(int), stream);
    deg_hist<<<(N_EDGES + 255) / 256, 256, 0, stream>>>(dst, deg);
    scan_block<<<NB, SCAN_B, 0, stream>>>(deg, rowptr, btot);
    scan_btot<<<1, 64, 0, stream>>>(btot, boff);
    scan_add<<<(N_NODES + 256) / 256, 256, 0, stream>>>(boff, rowptr, cursor);
    scatter_csr<<<(N_EDGES + 255) / 256, 256, 0, stream>>>(src, dst, cursor, csr_src);
    build_gptr<<<(N_NODES + 256) / 256, 256, 0, stream>>>(batch, gptr);

    // ---- weight + input split-bf16 conversion
    convert_x<<<(N_NODES * 64 + 255) / 256, 256, 0, stream>>>(x, Xh, Xl_, N_NODES * 64);
    for (int l = 0; l < 3; l++) {
        const int K = (l == 0) ? 64 : 128;
        convert_w<<<(256 * K + 255) / 256, 256, 0, stream>>>(
            (const float*)d_in[3 + 6 * l], (const float*)d_in[5 + 6 * l],
            Wth + l * 256 * 128, Wtl + l * 256 * 128, K);
    }

    const int gemm_grid = (N_NODES + 63) / 64;
    const int attn_grid = (N_NODES + 3) / 4;

    for (int l = 0; l < 3; l++) {
        const float* bl  = (const float*)d_in[4 + 6 * l];
        const float* br  = (const float*)d_in[6 + 6 * l];
        const float* att = (const float*)d_in[7 + 6 * l];
        const float* bb  = (const float*)d_in[8 + 6 * l];

        if (l == 0)
            gemm_mfma<64><<<gemm_grid, 256, 0, stream>>>(Xh, Xl_, Wth, Wtl,
                                                         bl, br, buf_xl, buf_xr, N_NODES);
        else
            gemm_mfma<128><<<gemm_grid, 256, 0, stream>>>(Xh, Xl_,
                                                          Wth + l * 256 * 128, Wtl + l * 256 * 128,
                                                          bl, br, buf_xl, buf_xr, N_NODES);
        node_attn<<<attn_grid, 256, 0, stream>>>(buf_xl, buf_xr, rowptr, csr_src,
                                                 att, bb, Xh, Xl_);
    }

    pool_head<<<GG / 4, 256, 0, stream>>>(Xh, Xl_, gptr, Wh, bh, out);
}